// Round 8
// baseline (444.069 us; speedup 1.0000x reference)
//
#include <hip/hip_runtime.h>
#include <stdint.h>

#define N_ROWS 65536
#define N_CLS  1000
#define KPAD   1024
#define FEAT   256
#define MT     64            // rows per block in GEMM kernels
#define NSTG   32            // k-stages of 32
#define NIT    16            // fallback: k-iterations of 64

typedef short bf16x8 __attribute__((ext_vector_type(8)));
typedef float f32x4  __attribute__((ext_vector_type(4)));

__device__ __forceinline__ ushort f32_to_bf16_rne(float f) {
    union { float f; uint32_t u; } x; x.f = f;
    uint32_t u = x.u + 0x7FFFu + ((x.u >> 16) & 1u);
    return (ushort)(u >> 16);
}

// Prep: centers -> bf16 in MFMA B-fragment order
//   Bfrag[s][w][nt][lane][j]  (k = s*32+quad*8+j, lane=quad*16+ml, n=w*64+nt*16+ml)
// csq[c] = ||centers[c]||^2 (zero-padded to KPAD) for the fallback path;
// csqB[e] = csq permuted to bitmask bit-order: class c = j2*256 + l*4 + i2,
//   dw=l>>1, h=l&1  ->  e = dw*32 + h*16 + j2*4 + i2   (bijective over 0..1023)
// so main2's t2 pass reads csqBS contiguously. Zero d_out.
__global__ __launch_bounds__(256) void prep_kernel(const float* __restrict__ centers,
                                                   ushort* __restrict__ Bfrag,
                                                   float* __restrict__ csq,
                                                   float* __restrict__ csqB,
                                                   float* __restrict__ out) {
    const int c = blockIdx.x;     // k index 0..1023
    const int n = threadIdx.x;    // n index 0..255
    float v = 0.f;
    if (c < N_CLS) v = centers[(size_t)c * FEAT + n];

    const int s    = c >> 5;
    const int quad = (c >> 3) & 3;
    const int j    = c & 7;
    const int w    = n >> 6;
    const int nt   = (n >> 4) & 3;
    const int ml   = n & 15;
    const int lane = quad * 16 + ml;
    const size_t idx = (((size_t)(s * 4 + w) * 4 + nt) * 64 + lane) * 8 + j;
    Bfrag[idx] = f32_to_bf16_rne(v);

    float sq = v * v;
    #pragma unroll
    for (int off = 32; off > 0; off >>= 1) sq += __shfl_down(sq, off);
    __shared__ float red[4];
    if ((threadIdx.x & 63) == 0) red[threadIdx.x >> 6] = sq;
    __syncthreads();
    if (threadIdx.x == 0) {
        const float total = red[0] + red[1] + red[2] + red[3];
        csq[c] = total;
        const int l   = (c & 255) >> 2;
        const int j2  = c >> 8;
        const int i2  = c & 3;
        csqB[(l >> 1) * 32 + (l & 1) * 16 + j2 * 4 + i2] = total;
        if (c == 0) out[0] = 0.f;
    }
}

// ======================= two-pass path (needs 8.92 MB ws) =======================

// Pass 1: PURE streaming compress — load, pack, store; nothing else.
// One wave per 8 consecutive rows. Lane l reads cols {j*256 + l*4 .. +3}
// (int4, coalesced 1 KB bursts). ushort[l] bit (j*4+i) <-> class j*256+l*4+i.
// No reductions, no scalar stores: rowcnt/t2 are recomputed in main2 from the
// staged bitmask (cheap, wave-uniform LDS broadcasts).
__global__ __launch_bounds__(256) void compress_kernel(const int* __restrict__ gt,
                                                       ushort* __restrict__ bitmask) {
    const int lane = threadIdx.x & 63;
    const int wid  = blockIdx.x * 4 + (threadIdx.x >> 6);   // 0..8191
    const int base = wid * 8;                                // rows base..base+7
    const bool v3  = (768 + lane * 4) < N_CLS;               // lane <= 57

    auto ldrow = [&](int row, int4 (&d)[4]) {
        const int* g = gt + (size_t)row * N_CLS + lane * 4;
        d[0] = *(const int4*)(g);
        d[1] = *(const int4*)(g + 256);
        d[2] = *(const int4*)(g + 512);
        d[3] = v3 ? *(const int4*)(g + 768) : make_int4(0, 0, 0, 0);
    };
    auto pack = [&](const int4 (&d)[4]) -> uint32_t {
        return (uint32_t)d[0].x        | ((uint32_t)d[0].y << 1)  | ((uint32_t)d[0].z << 2)  | ((uint32_t)d[0].w << 3)
            | ((uint32_t)d[1].x << 4)  | ((uint32_t)d[1].y << 5)  | ((uint32_t)d[1].z << 6)  | ((uint32_t)d[1].w << 7)
            | ((uint32_t)d[2].x << 8)  | ((uint32_t)d[2].y << 9)  | ((uint32_t)d[2].z << 10) | ((uint32_t)d[2].w << 11)
            | ((uint32_t)d[3].x << 12) | ((uint32_t)d[3].y << 13) | ((uint32_t)d[3].z << 14) | ((uint32_t)d[3].w << 15);
    };

    // depth-2 pipeline: one row always in flight while packing the previous
    int4 dP[4], dQ[4];
    ldrow(base, dP);
    ldrow(base + 1, dQ);
    #pragma unroll
    for (int rr = 0; rr < 8; rr += 2) {
        uint32_t p0 = pack(dP);
        if (rr + 2 < 8) ldrow(base + rr + 2, dP);
        bitmask[(size_t)(base + rr) * 64 + lane] = (ushort)p0;
        uint32_t p1 = pack(dQ);
        if (rr + 3 < 8) ldrow(base + rr + 3, dQ);
        bitmask[(size_t)(base + rr + 1) * 64 + lane] = (ushort)p1;
    }
}

// Pass 2: GEMM from bitmask. Stage bitmask rows (33-dword pitch) + bit-ordered
// csqB in LDS; compute rowcnt (popc) and t2 (bit-masked dot, contiguous float4
// LDS reads, wave-uniform -> broadcast) in the stage phase. MFMA loop: A-bits
// expanded in-register, B from the L2-resident fragment table (1 KB bursts,
// depth-2). No barriers in the main loop.
__global__ __launch_bounds__(256, 3) void main2_kernel(const ushort* __restrict__ bitmask,
                                                       const float* __restrict__ features,
                                                       const ushort* __restrict__ Bfrag,
                                                       const float* __restrict__ csqB,
                                                       float* __restrict__ out) {
    __shared__ uint32_t bmS[MT * 33];    // 8448 B
    __shared__ float    csqBS[KPAD];     // 4096 B
    __shared__ float    rcP[4][MT];      // 1024 B
    __shared__ float    t2P[4][MT];      // 1024 B
    __shared__ float    rcS[MT], t2S[MT], blockred[4];

    const int tid  = threadIdx.x;
    const int lane = tid & 63;
    const int w    = tid >> 6;
    const int ml   = lane & 15;
    const int quad = lane >> 4;
    const int m0   = blockIdx.x * MT;

    // ---- stage: bitmask rows (64 x 32 dwords, coalesced) + csqB ----
    const uint32_t* bm = (const uint32_t*)bitmask + (size_t)m0 * 32;
    #pragma unroll
    for (int i = 0; i < 8; i++) {
        int idx = i * 256 + tid;
        bmS[(idx >> 5) * 33 + (idx & 31)] = bm[idx];
    }
    *(float4*)&csqBS[tid * 4] = *(const float4*)&csqB[tid * 4];
    __syncthreads();

    // ---- rowcnt/t2 from bmS: thread = (row ri, dword-range part w) ----
    {
        const int ri = tid & 63;
        float rc = 0.f, t = 0.f;
        #pragma unroll
        for (int jj = 0; jj < 8; jj++) {
            const int dw = w * 8 + jj;                    // wave-uniform
            const uint32_t W = bmS[ri * 33 + dw];
            rc += (float)__popc(W);
            const float4* cb = (const float4*)&csqBS[dw * 32];
            #pragma unroll
            for (int q4 = 0; q4 < 8; q4++) {
                float4 c4 = cb[q4];                       // broadcast read
                t += ((W >> (q4 * 4 + 0)) & 1u) ? c4.x : 0.f;
                t += ((W >> (q4 * 4 + 1)) & 1u) ? c4.y : 0.f;
                t += ((W >> (q4 * 4 + 2)) & 1u) ? c4.z : 0.f;
                t += ((W >> (q4 * 4 + 3)) & 1u) ? c4.w : 0.f;
            }
        }
        rcP[w][ri] = rc;
        t2P[w][ri] = t;
    }
    __syncthreads();
    if (tid < MT) {
        rcS[tid] = rcP[0][tid] + rcP[1][tid] + rcP[2][tid] + rcP[3][tid];
        t2S[tid] = t2P[0][tid] + t2P[1][tid] + t2P[2][tid] + t2P[3][tid];
    }
    __syncthreads();

    f32x4 acc[4][4];
    #pragma unroll
    for (int i = 0; i < 4; i++)
        #pragma unroll
        for (int j = 0; j < 4; j++)
            #pragma unroll
            for (int k = 0; k < 4; k++) acc[i][j][k] = 0.f;

    const ushort* bb = Bfrag + ((size_t)w * 4 * 64 + lane) * 8;
    auto ld_B = [&](int s, bf16x8 (&b)[4]) {
        const ushort* p = bb + (size_t)s * 8192;
        b[0] = *(const bf16x8*)(p);
        b[1] = *(const bf16x8*)(p + 512);
        b[2] = *(const bf16x8*)(p + 1024);
        b[3] = *(const bf16x8*)(p + 1536);
    };

    // A-bit extraction: class c = s*32+quad*8+jj -> dword (s&7)*4+quad of the
    // row, bit (jj>>2)*16 + (s>>3)*4 + (jj&3).
    auto dostage = [&](int s, const bf16x8 (&b)[4]) {
        const int dw = (s & 7) * 4 + quad;
        const int sb = (s >> 3) * 4;
        #pragma unroll
        for (int mt = 0; mt < 4; mt++) {
            const uint32_t W = bmS[(mt * 16 + ml) * 33 + dw];
            union { uint32_t u[4]; bf16x8 v; } a;
            #pragma unroll
            for (int p = 0; p < 4; p++) {
                const int b0 = (p < 2) ? (sb + 2 * p) : (16 + sb + 2 * (p - 2));
                a.u[p] = ((W >> b0) & 1u) * 0x3F80u
                       | ((W >> (b0 + 1)) & 1u) * 0x3F800000u;
            }
            #pragma unroll
            for (int nt = 0; nt < 4; nt++)
                acc[mt][nt] = __builtin_amdgcn_mfma_f32_16x16x32_bf16(
                    a.v, b[nt], acc[mt][nt], 0, 0, 0);
        }
    };

    bf16x8 BfP[4], BfQ[4];
    ld_B(0, BfP);
    ld_B(1, BfQ);
    for (int s = 0; s < NSTG; s += 2) {
        dostage(s, BfP);
        if (s + 2 < NSTG) ld_B(s + 2, BfP);
        dostage(s + 1, BfQ);
        if (s + 3 < NSTG) ld_B(s + 3, BfQ);
    }

    float part = 0.f;
    #pragma unroll
    for (int mt = 0; mt < 4; mt++) {
        #pragma unroll
        for (int nt = 0; nt < 4; nt++) {
            const int n = w * 64 + nt * 16 + ml;
            #pragma unroll
            for (int reg = 0; reg < 4; reg++) {
                const int ri = mt * 16 + quad * 4 + reg;
                const float f = features[(size_t)(m0 + ri) * FEAT + n];
                part += f * (rcS[ri] * f - 2.f * acc[mt][nt][reg]) + t2S[ri] * (1.f / 256.f);
            }
        }
    }
    #pragma unroll
    for (int off = 32; off > 0; off >>= 1) part += __shfl_down(part, off);
    if (lane == 0) blockred[w] = part;
    __syncthreads();
    if (tid == 0)
        atomicAdd(out, (blockred[0] + blockred[1] + blockred[2] + blockred[3]) *
                           (1.f / (float)N_ROWS));
}

// ============== fallback path (R4 kernel, verified: 516 KB ws) ==============
__global__ __launch_bounds__(256, 3) void fused_kernel(const int* __restrict__ gt,
                                                       const float* __restrict__ features,
                                                       const ushort* __restrict__ Bfrag,
                                                       const float* __restrict__ csq,
                                                       float* __restrict__ out) {
    __shared__ ushort As[2 * 2 * 4 * 64 * 8];
    __shared__ float  csqS[KPAD];
    __shared__ float  rcS[256], t2S[256], rowcnt[MT], t2row[MT], blockred[4];

    const int tid  = threadIdx.x;
    const int m0   = blockIdx.x * MT;
    const int r    = tid >> 2;
    const int kc   = tid & 3;
    const int lane = tid & 63;
    const int w    = tid >> 6;
    const int ml   = lane & 15;
    const int quad = lane >> 4;

    f32x4 acc[4][4];
    #pragma unroll
    for (int i = 0; i < 4; i++)
        #pragma unroll
        for (int j = 0; j < 4; j++)
            #pragma unroll
            for (int k = 0; k < 4; k++) acc[i][j][k] = 0.f;

    int   rci = 0;
    float t2  = 0.f;
    const int* gtrow = gt + (size_t)(m0 + r) * N_CLS;

    const int mt_w = r >> 4, ml_w = r & 15;
    const int ks_w = kc >> 1, qb = (kc & 1) * 2;
    const int xw   = (ml_w >> 3) | (ks_w << 1) | ((kc & 1) << 2);
    const int slot0 = (((ks_w * 4 + mt_w) * 64) + (qb * 16 + ml_w)) ^ xw;
    const int slot1 = (((ks_w * 4 + mt_w) * 64) + ((qb + 1) * 16 + ml_w)) ^ xw;
    ushort* const wptr0 = As + slot0 * 8;
    ushort* const wptr1 = As + slot1 * 8;

    const int xr0 = ((lane >> 3) & 1) | (((lane >> 5) & 1) << 2);
    const int lx0 = (lane ^ xr0) * 8;
    const int lx1 = (lane ^ (xr0 | 2)) * 8;

    auto load_gt = [&](int it, int (&vv)[16]) {
        const int kb = it * 64 + kc * 16;
        if (kb + 16 <= N_CLS) {
            const int4* p = (const int4*)(gtrow + kb);
            int4 a0 = p[0], a1 = p[1], a2 = p[2], a3 = p[3];
            vv[0]=a0.x;  vv[1]=a0.y;  vv[2]=a0.z;  vv[3]=a0.w;
            vv[4]=a1.x;  vv[5]=a1.y;  vv[6]=a1.z;  vv[7]=a1.w;
            vv[8]=a2.x;  vv[9]=a2.y;  vv[10]=a2.z; vv[11]=a2.w;
            vv[12]=a3.x; vv[13]=a3.y; vv[14]=a3.z; vv[15]=a3.w;
        } else {
            #pragma unroll
            for (int j = 0; j < 16; j++) {
                int k = kb + j;
                vv[j] = (k < N_CLS) ? gtrow[k] : 0;
            }
        }
    };

    auto convert_store = [&](int buf, int it, const int (&vv)[16]) {
        const int kb = it * 64 + kc * 16;
        const float4* cp = (const float4*)&csqS[kb];
        float4 q0 = cp[0], q1 = cp[1], q2 = cp[2], q3 = cp[3];
        float cs[16] = {q0.x,q0.y,q0.z,q0.w, q1.x,q1.y,q1.z,q1.w,
                        q2.x,q2.y,q2.z,q2.w, q3.x,q3.y,q3.z,q3.w};
        uint32_t u[8];
        #pragma unroll
        for (int j = 0; j < 8; j++)
            u[j] = (uint32_t)(vv[2*j] + (vv[2*j+1] << 16)) * 0x3F80u;
        #pragma unroll
        for (int j = 0; j < 16; j++) { rci += vv[j]; t2 += (float)vv[j] * cs[j]; }
        uint4* d0 = (uint4*)(wptr0 + buf * 4096);
        uint4* d1 = (uint4*)(wptr1 + buf * 4096);
        *d0 = make_uint4(u[0], u[1], u[2], u[3]);
        *d1 = make_uint4(u[4], u[5], u[6], u[7]);
    };

    const ushort* bbase = Bfrag + ((size_t)w * 4) * 64 * 8 + (size_t)lane * 8;
    auto mfma_iter = [&](int buf, int it) {
        bf16x8 b0[4], b1[4];
        const ushort* p0 = bbase + (size_t)(it * 2 + 0) * (4 * 4 * 64 * 8);
        const ushort* p1 = bbase + (size_t)(it * 2 + 1) * (4 * 4 * 64 * 8);
        #pragma unroll
        for (int nt = 0; nt < 4; ++nt) b0[nt] = *(const bf16x8*)(p0 + nt * 64 * 8);
        #pragma unroll
        for (int nt = 0; nt < 4; ++nt) b1[nt] = *(const bf16x8*)(p1 + nt * 64 * 8);
        #pragma unroll
        for (int ks = 0; ks < 2; ++ks) {
            const int lx = ks ? lx1 : lx0;
            bf16x8 af[4];
            #pragma unroll
            for (int mt = 0; mt < 4; mt++)
                af[mt] = *(const bf16x8*)(As + buf * 4096 + (ks * 4 + mt) * 512 + lx);
            #pragma unroll
            for (int mt = 0; mt < 4; mt++)
                #pragma unroll
                for (int nt = 0; nt < 4; nt++)
                    acc[mt][nt] = __builtin_amdgcn_mfma_f32_16x16x32_bf16(
                        af[mt], ks ? b1[nt] : b0[nt], acc[mt][nt], 0, 0, 0);
        }
    };

    int gtA[16], gtB[16];
    {
        *(float4*)&csqS[tid * 4] = *(const float4*)&csq[tid * 4];
        load_gt(0, gtA);
        __syncthreads();
        convert_store(0, 0, gtA);
        load_gt(1, gtA);
        __syncthreads();
    }
    for (int it = 0; it < NIT; it += 2) {
        if (it + 2 < NIT) load_gt(it + 2, gtB);
        mfma_iter(0, it);
        if (it + 1 < NIT) convert_store(1, it + 1, gtA);
        __syncthreads();
        if (it + 3 < NIT) load_gt(it + 3, gtA);
        mfma_iter(1, it + 1);
        if (it + 2 < NIT) convert_store(0, it + 2, gtB);
        __syncthreads();
    }

    rcS[tid] = (float)rci;
    t2S[tid] = t2;
    __syncthreads();
    if (tid < MT) {
        rowcnt[tid] = rcS[tid*4] + rcS[tid*4+1] + rcS[tid*4+2] + rcS[tid*4+3];
        t2row[tid]  = t2S[tid*4] + t2S[tid*4+1] + t2S[tid*4+2] + t2S[tid*4+3];
    }
    __syncthreads();

    float part = 0.f;
    #pragma unroll
    for (int mt = 0; mt < 4; mt++) {
        #pragma unroll
        for (int nt = 0; nt < 4; nt++) {
            const int n = w * 64 + nt * 16 + ml;
            #pragma unroll
            for (int reg = 0; reg < 4; reg++) {
                const int ri = mt * 16 + quad * 4 + reg;
                const float f = features[(size_t)(m0 + ri) * FEAT + n];
                part += f * (rowcnt[ri] * f - 2.f * acc[mt][nt][reg]) + t2row[ri] * (1.f / 256.f);
            }
        }
    }
    #pragma unroll
    for (int off = 32; off > 0; off >>= 1) part += __shfl_down(part, off);
    if (lane == 0) blockred[w] = part;
    __syncthreads();
    if (tid == 0)
        atomicAdd(out, (blockred[0] + blockred[1] + blockred[2] + blockred[3]) *
                           (1.f / (float)N_ROWS));
}

extern "C" void kernel_launch(void* const* d_in, const int* in_sizes, int n_in,
                              void* d_out, int out_size, void* d_ws, size_t ws_size,
                              hipStream_t stream) {
    const int*   gt       = (const int*)d_in[0];
    const float* features = (const float*)d_in[1];
    const float* centers  = (const float*)d_in[2];
    float*       out      = (float*)d_out;

    char* ws = (char*)d_ws;
    ushort* Bfrag = (ushort*)(ws);                    // [0, 524288)
    float*  csq   = (float*)(ws + 524288);            // [524288, 528384)
    float*  csqB  = (float*)(ws + 528384);            // [528384, 532480)

    prep_kernel<<<KPAD, 256, 0, stream>>>(centers, Bfrag, csq, csqB, out);

    const size_t REQ = 532480u + 8388608u;            // 8,921,088 B
    if (ws_size >= REQ) {
        ushort* bitmask = (ushort*)(ws + 532480);
        compress_kernel<<<2048, 256, 0, stream>>>(gt, bitmask);
        main2_kernel<<<N_ROWS / MT, 256, 0, stream>>>(bitmask, features, Bfrag,
                                                      csqB, out);
    } else {
        fused_kernel<<<N_ROWS / MT, 256, 0, stream>>>(gt, features, Bfrag, csq, out);
    }
}

// Round 10
// 412.784 us; speedup vs baseline: 1.0758x; 1.0758x over previous
//
#include <hip/hip_runtime.h>
#include <stdint.h>

#define N_ROWS 65536
#define N_CLS  1000
#define KPAD   1024
#define FEAT   256
#define MT     128         // rows per block (2x R0; B tile shared by 8 waves)
#define BK     64          // k per iteration
#define NIT    (KPAD/BK)   // 16
#define LDA    72          // padded LDS stride (bf16): 144 B
#define LDB    72
#define NTHR   512

typedef short bf16x8 __attribute__((ext_vector_type(8)));
typedef float f32x4  __attribute__((ext_vector_type(4)));

__device__ __forceinline__ ushort f32_to_bf16_rne(float f) {
    union { float f; uint32_t u; } x; x.f = f;
    uint32_t u = x.u + 0x7FFFu + ((x.u >> 16) & 1u);
    return (ushort)(u >> 16);
}

// Prep (R0 verbatim): centersT[n][c] = bf16(centers[c][n]) zero-padded to KPAD;
// csq[c] = ||centers[c]||^2; zero d_out.
__global__ __launch_bounds__(256) void prep_kernel(const float* __restrict__ centers,
                                                   ushort* __restrict__ centersT,
                                                   float* __restrict__ csq,
                                                   float* __restrict__ out) {
    const int c = blockIdx.x;     // 0..1023
    const int n = threadIdx.x;    // 0..255
    float v = 0.f;
    if (c < N_CLS) v = centers[(size_t)c * FEAT + n];
    centersT[(size_t)n * KPAD + c] = f32_to_bf16_rne(v);
    float sq = v * v;
    #pragma unroll
    for (int off = 32; off > 0; off >>= 1) sq += __shfl_down(sq, off);
    __shared__ float red[4];
    if ((threadIdx.x & 63) == 0) red[threadIdx.x >> 6] = sq;
    __syncthreads();
    if (threadIdx.x == 0) {
        csq[c] = red[0] + red[1] + red[2] + red[3];
        if (c == 0) out[0] = 0.f;
    }
}

// R0 structure scaled to MT=128 / 512 threads + depth-2 gt prefetch:
//  - 8 waves (2 row-halves x 4 col-groups), per-wave tile 64x64 (acc = 64 regs,
//    identical to R0 -> same spill-free envelope; cap 256 at (512,2)).
//  - B tile (256 cols x 64 k) staged once per iter, shared by 8 waves:
//    B global re-traffic halves vs R0 (256 MB total), per-wave stage cost halves.
//  - gt(it+2) held in raw int4 registers, issued AFTER this iter's B staging
//    (newest in vmcnt FIFO -> not drained by B's waits); consumed (pack+rc+t2+
//    LDS write) two iterations later: ~1.5 iters of HBM-latency cover.
//  - 2 barriers/iter (R0-proven); csq staged once in LDS.
__global__ __launch_bounds__(NTHR, 2) void main_kernel(const int* __restrict__ gt,
                                                       const float* __restrict__ features,
                                                       const ushort* __restrict__ centersT,
                                                       const float* __restrict__ csq,
                                                       float* __restrict__ out) {
    __shared__ ushort As[MT * LDA];     // 18432 B
    __shared__ ushort Bs[FEAT * LDB];   // 36864 B
    __shared__ float  csqS[KPAD];       // 4096 B
    __shared__ float  rcS[NTHR];        // 2048 B
    __shared__ float  t2S[NTHR];        // 2048 B
    __shared__ float  rowcnt[MT];       // 512 B
    __shared__ float  t2row[MT];        // 512 B
    __shared__ float  blockred[8];      // total 64544 B (< 64 KiB static limit)

    const int tid  = threadIdx.x;
    const int m0   = blockIdx.x * MT;
    const int r    = tid >> 2;       // staging row 0..127
    const int kc   = tid & 3;        // staging k-quarter (16 ints)
    const int lane = tid & 63;
    const int w    = tid >> 6;       // wave 0..7
    const int mh   = w >> 2;         // row-half 0..1
    const int wn   = w & 3;          // col-group 0..3 -> cols wn*64
    const int ml   = lane & 15;
    const int quad = lane >> 4;

    f32x4 acc[4][4];
    #pragma unroll
    for (int i = 0; i < 4; i++)
        #pragma unroll
        for (int j = 0; j < 4; j++)
            #pragma unroll
            for (int k = 0; k < 4; k++) acc[i][j][k] = 0.f;

    float rc = 0.f, t2 = 0.f;
    const int* gtrow = gt + (size_t)(m0 + r) * N_CLS;

    auto load_gt = [&](int it, int4 (&d)[4]) {
        const int kb = it * BK + kc * 16;
        if (kb + 16 <= N_CLS) {
            const int4* p = (const int4*)(gtrow + kb);
            d[0] = p[0]; d[1] = p[1]; d[2] = p[2]; d[3] = p[3];
        } else {
            int tmp[16];
            #pragma unroll
            for (int j = 0; j < 16; j++) {
                int k = kb + j;
                tmp[j] = (k < N_CLS) ? gtrow[k] : 0;
            }
            d[0] = make_int4(tmp[0], tmp[1], tmp[2], tmp[3]);
            d[1] = make_int4(tmp[4], tmp[5], tmp[6], tmp[7]);
            d[2] = make_int4(tmp[8], tmp[9], tmp[10], tmp[11]);
            d[3] = make_int4(tmp[12], tmp[13], tmp[14], tmp[15]);
        }
    };

    auto convert_store = [&](int it, const int4 (&d)[4]) {
        const int kb = it * BK + kc * 16;
        const float4* cp = (const float4*)&csqS[kb];   // zero-padded, broadcast-ish
        float4 q0 = cp[0], q1 = cp[1], q2 = cp[2], q3 = cp[3];
        float cs[16] = {q0.x,q0.y,q0.z,q0.w, q1.x,q1.y,q1.z,q1.w,
                        q2.x,q2.y,q2.z,q2.w, q3.x,q3.y,q3.z,q3.w};
        int v[16] = {d[0].x,d[0].y,d[0].z,d[0].w, d[1].x,d[1].y,d[1].z,d[1].w,
                     d[2].x,d[2].y,d[2].z,d[2].w, d[3].x,d[3].y,d[3].z,d[3].w};
        uint32_t u[8];
        #pragma unroll
        for (int j = 0; j < 8; j++)   // v in {0,1}: pack 2x bf16(1.0)
            u[j] = (uint32_t)(v[2*j] + (v[2*j+1] << 16)) * 0x3F80u;
        #pragma unroll
        for (int j = 0; j < 16; j++) {
            rc += v[j] ? 1.f : 0.f;
            t2 += v[j] ? cs[j] : 0.f;
        }
        uint4* dst = (uint4*)&As[r * LDA + kc * 16];
        dst[0] = make_uint4(u[0], u[1], u[2], u[3]);
        dst[1] = make_uint4(u[4], u[5], u[6], u[7]);
    };

    auto stage_B = [&](int it) {
        const int k0 = it * BK;
        #pragma unroll
        for (int j = 0; j < 4; j++) {
            int g = j * NTHR + tid;      // 2048 chunks of 16 B
            int n = g >> 3;
            int kcb = g & 7;
            *(uint4*)&Bs[n * LDB + kcb * 8] =
                *(const uint4*)&centersT[(size_t)n * KPAD + k0 + kcb * 8];
        }
    };

    auto mfma_iter = [&]() {
        #pragma unroll
        for (int ks = 0; ks < 2; ++ks) {
            const int kk = ks * 32 + quad * 8;
            bf16x8 af[4], bfr[4];
            #pragma unroll
            for (int mt = 0; mt < 4; mt++)
                af[mt] = *(const bf16x8*)&As[(mh * 64 + mt * 16 + ml) * LDA + kk];
            #pragma unroll
            for (int nt = 0; nt < 4; nt++)
                bfr[nt] = *(const bf16x8*)&Bs[(wn * 64 + nt * 16 + ml) * LDB + kk];
            #pragma unroll
            for (int mt = 0; mt < 4; mt++)
                #pragma unroll
                for (int nt = 0; nt < 4; nt++)
                    acc[mt][nt] = __builtin_amdgcn_mfma_f32_16x16x32_bf16(
                        af[mt], bfr[nt], acc[mt][nt], 0, 0, 0);
        }
    };

    // ---- prologue: csq -> LDS; prefetch gt(0), gt(1) ----
    int4 P[4], Q[4];
    *(float2*)&csqS[tid * 2] = *(const float2*)&csq[tid * 2];
    load_gt(0, P);
    load_gt(1, Q);
    __syncthreads();                 // csqS visible

    for (int it = 0; it < NIT; it += 2) {
        // even sub-iter: consume P
        convert_store(it, P);        // pack + rc/t2 + As write (P already landed)
        stage_B(it);
        if (it + 2 < NIT) load_gt(it + 2, P);   // issued last -> rides across MFMA+next iter
        __syncthreads();
        mfma_iter();
        __syncthreads();

        // odd sub-iter: consume Q
        convert_store(it + 1, Q);
        stage_B(it + 1);
        if (it + 3 < NIT) load_gt(it + 3, Q);
        __syncthreads();
        mfma_iter();
        __syncthreads();
    }

    // ---- per-row reductions ----
    rcS[tid] = rc;
    t2S[tid] = t2;
    __syncthreads();
    if (tid < MT) {
        rowcnt[tid] = rcS[tid*4] + rcS[tid*4+1] + rcS[tid*4+2] + rcS[tid*4+3];
        t2row[tid]  = t2S[tid*4] + t2S[tid*4+1] + t2S[tid*4+2] + t2S[tid*4+3];
    }
    __syncthreads();

    // ---- epilogue: read features once, fold all three terms ----
    float part = 0.f;
    #pragma unroll
    for (int mt = 0; mt < 4; mt++) {
        #pragma unroll
        for (int nt = 0; nt < 4; nt++) {
            const int n = wn * 64 + nt * 16 + ml;
            #pragma unroll
            for (int reg = 0; reg < 4; reg++) {
                const int ri = mh * 64 + mt * 16 + quad * 4 + reg;
                const float f = features[(size_t)(m0 + ri) * FEAT + n];
                const float T = acc[mt][nt][reg];
                part += f * (rowcnt[ri] * f - 2.f * T) + t2row[ri] * (1.f / 256.f);
            }
        }
    }
    #pragma unroll
    for (int off = 32; off > 0; off >>= 1) part += __shfl_down(part, off);
    if (lane == 0) blockred[w] = part;
    __syncthreads();
    if (tid == 0) {
        float s = blockred[0] + blockred[1] + blockred[2] + blockred[3]
                + blockred[4] + blockred[5] + blockred[6] + blockred[7];
        atomicAdd(out, s * (1.f / (float)N_ROWS));
    }
}

extern "C" void kernel_launch(void* const* d_in, const int* in_sizes, int n_in,
                              void* d_out, int out_size, void* d_ws, size_t ws_size,
                              hipStream_t stream) {
    const int*   gt       = (const int*)d_in[0];
    const float* features = (const float*)d_in[1];
    const float* centers  = (const float*)d_in[2];
    float*       out      = (float*)d_out;

    ushort* centersT = (ushort*)d_ws;                                   // 512 KB
    float*  csq      = (float*)((char*)d_ws + (size_t)FEAT * KPAD * 2); // 4 KB

    prep_kernel<<<KPAD, 256, 0, stream>>>(centers, centersT, csq, out);
    main_kernel<<<N_ROWS / MT, NTHR, 0, stream>>>(gt, features, centersT, csq, out);
}